// Round 4
// baseline (151.178 us; speedup 1.0000x reference)
//
#include <hip/hip_runtime.h>
#include <hip/hip_bf16.h>

// ---- problem constants ----
#define B_IMG   128
#define CH      3
#define HW      224
#define NPATCH  196          // tokens per image
#define TOKENS  25088        // B_IMG * NPATCH
#define PATCH   16
#define FDIM    768          // C*P*P (K of the GEMM)
#define DDIM    768          // output embed dim (N of the GEMM)
#define TOKELEMS ((size_t)TOKENS * FDIM)
#define OUT_TOKENS ((size_t)TOKENS * DDIM)     // positions follow in d_out

#define GATHER_BLOCKS (TOKENS * (FDIM / 4) / 256)   // 18816
#define WCONV_BLOCKS  ((DDIM * FDIM / 4) / 256)     // 576

typedef short short8 __attribute__((ext_vector_type(8)));
typedef float f32x4  __attribute__((ext_vector_type(4)));

static __device__ __forceinline__ unsigned short f2bf(float v) {
  unsigned u = __float_as_uint(v);
  unsigned r = u + 0x7fffu + ((u >> 16) & 1u);
  return (unsigned short)(r >> 16);
}

// ---- kernel 1: gather patches -> bf16 [TOKENS][768] + positions, W -> bf16 ----
// (HBM-roofline bound already: ~120 MB moved, ~20us)
__global__ __launch_bounds__(256) void prep_kernel(
    const float* __restrict__ x, const int* __restrict__ ys,
    const int* __restrict__ xs, const float* __restrict__ W,
    short* __restrict__ patches, short* __restrict__ Wbf,
    float* __restrict__ pos) {
  const int blk = blockIdx.x;
  if (blk < GATHER_BLOCKS) {
    int e   = blk * 256 + threadIdx.x;      // quad index
    int tok = e / 192;
    int q   = e - tok * 192;
    int f   = q * 4;
    int b   = tok / NPATCH;
    int y   = ys[tok];
    int xc  = xs[tok];
    int c   = f >> 8;
    int rem = f & 255;
    int py  = rem >> 4;
    int px  = rem & 15;
    const float* src = x + ((size_t)(b * CH + c) * HW + (y + py)) * HW + xc + px;
    ushort4 o;
    o.x = f2bf(src[0]); o.y = f2bf(src[1]); o.z = f2bf(src[2]); o.w = f2bf(src[3]);
    *(ushort4*)&patches[(size_t)tok * FDIM + f] = o;
    if (q == 0) {
      pos[(size_t)tok * 2]     = (float)y;
      pos[(size_t)tok * 2 + 1] = (float)xc;
    }
  } else {
    int i = ((blk - GATHER_BLOCKS) * 256 + threadIdx.x) * 4;
    float4 v = *(const float4*)&W[i];
    ushort4 o;
    o.x = f2bf(v.x); o.y = f2bf(v.y); o.z = f2bf(v.z); o.w = f2bf(v.w);
    *(ushort4*)&Wbf[i] = o;
  }
}

// ---- kernel 2: pure-register bf16 MFMA GEMM — NO LDS, NO barriers ----
// R3 post-mortem: LDS staging round-trip (8 ds_read_b128 + lds-writes per
// K-step vs only 78cy MFMA) was the invariant ~30us cost across all three
// schedules, and B (1.2MB) is L2-resident anyway (Common-mistake #7).
// Each wave independently owns a 64x64 output tile: 4x4 x mfma_16x16x32,
// fragments loaded global->VGPR (16 rows x 64B lines = same L2 line count
// as coalesced), register double-buffered, waves free-run (12 waves/CU TLP
// hides L2 latency; no sync anywhere).
__global__ __launch_bounds__(256) void gemm_kernel(
    const short* __restrict__ A,    // patches bf16 [TOKENS][768]
    const short* __restrict__ Bw,   // Wbf bf16 [768][768]
    const float* __restrict__ bias,
    float* __restrict__ C) {
  const int tid = threadIdx.x;
  const int w   = tid >> 6;
  const int l   = tid & 63;
  const int lr  = l & 15;
  const int lg  = l >> 4;

  // XCD swizzle (1176 = 8*147, bijective): each XCD gets 588 consecutive
  // wave-jobs = 49 full A row-panels -> A panel read once per XCD L2.
  const int id  = blockIdx.x;
  const int nid = (id & 7) * 147 + (id >> 3);
  const int job = nid * 4 + w;            // 0..4703 wave-jobs
  const int mt  = job / 12;               // 392 M-tiles of 64
  const int nt  = job - mt * 12;          // 12 N-tiles of 64
  const int m0  = mt * 64;
  const int n0  = nt * 64;

  const short* gA = A  + (size_t)(m0 + lr) * FDIM + lg * 8;
  const short* gB = Bw + (size_t)(n0 + lr) * FDIM + lg * 8;

  float bs[4];
#pragma unroll
  for (int ni = 0; ni < 4; ++ni) bs[ni] = bias[n0 + ni * 16 + lr];

  f32x4 acc[4][4];
  const f32x4 z = {0.f, 0.f, 0.f, 0.f};
#pragma unroll
  for (int mi = 0; mi < 4; ++mi)
#pragma unroll
    for (int ni = 0; ni < 4; ++ni) acc[mi][ni] = z;

  // named fragment sets (static indexing only — rule #20)
  short8 A0[4], B0[4], A1[4], B1[4];

#define LOADSET(Af, Bf, kt)                                                  \
  do {                                                                       \
    const short* pa = gA + (kt) * 32;                                        \
    const short* pb = gB + (kt) * 32;                                        \
    _Pragma("unroll")                                                        \
    for (int i = 0; i < 4; ++i) Af[i] = *(const short8*)(pa + i * 16 * FDIM);\
    _Pragma("unroll")                                                        \
    for (int i = 0; i < 4; ++i) Bf[i] = *(const short8*)(pb + i * 16 * FDIM);\
  } while (0)

#define MFMASET(Af, Bf)                                                      \
  do {                                                                       \
    _Pragma("unroll")                                                        \
    for (int mi = 0; mi < 4; ++mi)                                           \
      _Pragma("unroll")                                                      \
      for (int ni = 0; ni < 4; ++ni)                                         \
        acc[mi][ni] = __builtin_amdgcn_mfma_f32_16x16x32_bf16(               \
            Af[mi], Bf[ni], acc[mi][ni], 0, 0, 0);                           \
  } while (0)

  LOADSET(A0, B0, 0);
  for (int kt = 0; kt < 24; kt += 2) {
    LOADSET(A1, B1, kt + 1);          // issue next set before computing
    MFMASET(A0, B0);
    const int k2 = (kt + 2 < 24) ? kt + 2 : 0;   // last iter: harmless reload
    LOADSET(A0, B0, k2);
    MFMASET(A1, B1);
  }

  // epilogue: C/D layout col = lane&15, row = (lane>>4)*4 + j
#pragma unroll
  for (int ni = 0; ni < 4; ++ni) {
    const int col = n0 + ni * 16 + lr;
#pragma unroll
    for (int mi = 0; mi < 4; ++mi) {
      const int row = m0 + mi * 16 + lg * 4;
      const f32x4 v = acc[mi][ni];
#pragma unroll
      for (int j = 0; j < 4; ++j)
        C[(size_t)(row + j) * DDIM + col] = v[j] + bs[ni];
    }
  }
#undef LOADSET
#undef MFMASET
}

// ---- fallback (ws too small): naive fused f32, correct but slow ----
__global__ __launch_bounds__(256) void naive_kernel(
    const float* __restrict__ x, const int* __restrict__ ys,
    const int* __restrict__ xs, const float* __restrict__ W,
    const float* __restrict__ bias, float* __restrict__ out) {
  __shared__ float prow[FDIM];
  const int tok = blockIdx.x;
  const int t   = threadIdx.x;
  const int b   = tok / NPATCH;
  const int y   = ys[tok];
  const int xc  = xs[tok];
  for (int i = t; i < FDIM; i += 256) {
    int c = i >> 8, rem = i & 255, py = rem >> 4, px = rem & 15;
    prow[i] = x[((size_t)(b * CH + c) * HW + y + py) * HW + xc + px];
  }
  __syncthreads();
  for (int dd = 0; dd < 3; ++dd) {
    const int d = t + dd * 256;
    float s = bias[d];
    const float4* wr = (const float4*)&W[(size_t)d * FDIM];
    const float4* pr = (const float4*)prow;
    for (int f4 = 0; f4 < FDIM / 4; ++f4) {
      float4 wv = wr[f4];
      float4 pv = pr[f4];
      s += wv.x * pv.x + wv.y * pv.y + wv.z * pv.z + wv.w * pv.w;
    }
    out[(size_t)tok * DDIM + d] = s;
  }
  if (t == 0) {
    float* pos = out + OUT_TOKENS;
    pos[(size_t)tok * 2]     = (float)y;
    pos[(size_t)tok * 2 + 1] = (float)xc;
  }
}

extern "C" void kernel_launch(void* const* d_in, const int* in_sizes, int n_in,
                              void* d_out, int out_size, void* d_ws, size_t ws_size,
                              hipStream_t stream) {
  const float* x    = (const float*)d_in[0];
  const int*   ys   = (const int*)d_in[1];
  const int*   xs   = (const int*)d_in[2];
  const float* W    = (const float*)d_in[3];
  const float* bias = (const float*)d_in[4];
  float* out = (float*)d_out;
  float* pos = out + OUT_TOKENS;

  const size_t w_bytes = (size_t)DDIM * FDIM * 2;
  const size_t p_bytes = TOKELEMS * 2;
  if (ws_size >= w_bytes + p_bytes) {
    short* Wbf     = (short*)d_ws;
    short* patches = (short*)d_ws + (size_t)DDIM * FDIM;
    prep_kernel<<<GATHER_BLOCKS + WCONV_BLOCKS, 256, 0, stream>>>(
        x, ys, xs, W, patches, Wbf, pos);
    gemm_kernel<<<(TOKENS / 64 / 4) * (DDIM / 64), 256, 0, stream>>>(
        patches, Wbf, bias, out);
  } else {
    naive_kernel<<<TOKENS, 256, 0, stream>>>(x, ys, xs, W, bias, out);
  }
}

// Round 5
// 93.652 us; speedup vs baseline: 1.6143x; 1.6143x over previous
//
#include <hip/hip_runtime.h>
#include <hip/hip_bf16.h>

// ---- problem constants ----
#define B_IMG   128
#define CH      3
#define HW      224
#define NPATCH  196          // tokens per image
#define TOKENS  25088        // B_IMG * NPATCH
#define PATCH   16
#define FDIM    768          // C*P*P (K of the GEMM)
#define DDIM    768          // output embed dim (N of the GEMM)
#define TOKELEMS ((size_t)TOKENS * FDIM)
#define OUT_TOKENS ((size_t)TOKENS * DDIM)     // positions follow in d_out

#define GATHER_BLOCKS (TOKENS * (FDIM / 4) / 256)   // 18816
#define WCONV_BLOCKS  ((DDIM * FDIM / 4) / 256)     // 576

typedef short short8 __attribute__((ext_vector_type(8)));
typedef float f32x4  __attribute__((ext_vector_type(4)));

static __device__ __forceinline__ unsigned short f2bf(float v) {
  unsigned u = __float_as_uint(v);
  unsigned r = u + 0x7fffu + ((u >> 16) & 1u);
  return (unsigned short)(r >> 16);
}

static __device__ __forceinline__ void gload16(const short* g, short* l) {
  __builtin_amdgcn_global_load_lds(
      (const __attribute__((address_space(1))) void*)g,
      (__attribute__((address_space(3))) void*)l,
      16, 0, 0);
}

// ---- kernel 1: gather patches -> bf16 [TOKENS][768] + positions, W -> bf16 ----
__global__ __launch_bounds__(256) void prep_kernel(
    const float* __restrict__ x, const int* __restrict__ ys,
    const int* __restrict__ xs, const float* __restrict__ W,
    short* __restrict__ patches, short* __restrict__ Wbf,
    float* __restrict__ pos) {
  const int blk = blockIdx.x;
  if (blk < GATHER_BLOCKS) {
    int e   = blk * 256 + threadIdx.x;      // quad index
    int tok = e / 192;
    int q   = e - tok * 192;
    int f   = q * 4;
    int b   = tok / NPATCH;
    int y   = ys[tok];
    int xc  = xs[tok];
    int c   = f >> 8;
    int rem = f & 255;
    int py  = rem >> 4;
    int px  = rem & 15;
    const float* src = x + ((size_t)(b * CH + c) * HW + (y + py)) * HW + xc + px;
    ushort4 o;
    o.x = f2bf(src[0]); o.y = f2bf(src[1]); o.z = f2bf(src[2]); o.w = f2bf(src[3]);
    *(ushort4*)&patches[(size_t)tok * FDIM + f] = o;
    if (q == 0) {
      pos[(size_t)tok * 2]     = (float)y;
      pos[(size_t)tok * 2 + 1] = (float)xc;
    }
  } else {
    int i = ((blk - GATHER_BLOCKS) * 256 + threadIdx.x) * 4;
    float4 v = *(const float4*)&W[i];
    ushort4 o;
    o.x = f2bf(v.x); o.y = f2bf(v.y); o.z = f2bf(v.z); o.w = f2bf(v.w);
    *(ushort4*)&Wbf[i] = o;
  }
}

// ---- kernel 2: 256x128-tile 8-wave ring-4 MFMA GEMM ----
// R4 post-mortem: no-LDS variant was L2-request-rate bound (16 segments per
// fragment load instruction -> 123us). Back to LDS staging, but in the
// 256-class structure: 8 waves (4M x 2N, wave tile 64x64), BK=32 subtiles in
// a ring-4 (96KB LDS), consumption-aligned staging (each wave stages exactly
// the A-quarter rows + B rows it consumes: 3 gload16/step), counted vmcnt(9)
// so loads span 3 steps (never drained in the main loop), raw s_barrier.
__global__ __launch_bounds__(512) void gemm_kernel(
    const short* __restrict__ A,    // patches bf16 [TOKENS][768]
    const short* __restrict__ Bw,   // Wbf bf16 [768][768]
    const float* __restrict__ bias,
    float* __restrict__ C) {
  __shared__ short As[4][256 * 32];   // 64KB
  __shared__ short Bs[4][128 * 32];   // 32KB

  const int tid = threadIdx.x;
  const int w   = tid >> 6;      // 0..7
  const int l   = tid & 63;
  const int wr  = w >> 1;        // 0..3  M-quarter of the block tile
  const int wc  = w & 1;         // 0..1  N-half
  const int lr  = l & 15;
  const int lg  = l >> 4;

  // bijective XCD swizzle for 588 blocks (m204 variant: q=73, r=4):
  // consecutive nid within an XCD chunk share A row-panels -> L2 reuse.
  const int id   = blockIdx.x;
  const int xcd  = id & 7;
  const int chnk = id >> 3;
  const int nid  = (xcd < 4 ? xcd * 74 : 4 * 74 + (xcd - 4) * 73) + chnk;
  const int mt   = nid / 6;
  const int nt   = nid - mt * 6;
  const int m0   = mt * 256;
  const int n0   = nt * 128;

  f32x4 acc[4][4];
  const f32x4 z = {0.f, 0.f, 0.f, 0.f};
#pragma unroll
  for (int mi = 0; mi < 4; ++mi)
#pragma unroll
    for (int ni = 0; ni < 4; ++ni) acc[mi][ni] = z;

  // bias pinned complete before staging (keeps the vmcnt queue clean)
  float bs[4];
#pragma unroll
  for (int ni = 0; ni < 4; ++ni)
    bs[ni] = bias[n0 + wc * 64 + ni * 16 + lr];
#pragma unroll
  for (int ni = 0; ni < 4; ++ni) asm volatile("" : "+v"(bs[ni]));

  // staging addresses (consumption-aligned):
  // A: wave stages rows [m0 + wr*64 + wc*32, +32) — the half of its own
  //    A-quarter this wave covers (2 gload16 of 16 rows each).
  // B: wave stages rows [n0 + wc*64 + wr*16, +16) — inside its own B-half.
  const short* gA = A  + (size_t)(m0 + wr * 64 + wc * 32 + (l >> 2)) * FDIM + ((l & 3) << 3);
  const short* gB = Bw + (size_t)(n0 + wc * 64 + wr * 16 + (l >> 2)) * FDIM + ((l & 3) << 3);
  const int lAoff = (wr * 64 + wc * 32) * 32;   // shorts; lane lands at +l*8
  const int lBoff = (wc * 64 + wr * 16) * 32;

  auto stage = [&](int slot, int s) {
    const int ko = s * 32;
    short* lA = &As[slot][lAoff];
    short* lB = &Bs[slot][lBoff];
    gload16(gA + ko, lA);
    gload16(gA + 16 * FDIM + ko, lA + 16 * 32);
    gload16(gB + ko, lB);
  };
  auto compute = [&](int slot) {
    const short* Ab = As[slot];
    const short* Bb = Bs[slot];
    short8 a[4], b[4];
    const int koff = lg * 8;
#pragma unroll
    for (int mi = 0; mi < 4; ++mi)
      a[mi] = *(const short8*)&Ab[(wr * 64 + mi * 16 + lr) * 32 + koff];
#pragma unroll
    for (int ni = 0; ni < 4; ++ni)
      b[ni] = *(const short8*)&Bb[(wc * 64 + ni * 16 + lr) * 32 + koff];
    __builtin_amdgcn_s_setprio(1);
#pragma unroll
    for (int mi = 0; mi < 4; ++mi)
#pragma unroll
      for (int ni = 0; ni < 4; ++ni)
        acc[mi][ni] =
            __builtin_amdgcn_mfma_f32_16x16x32_bf16(a[mi], b[ni], acc[mi][ni], 0, 0, 0);
    __builtin_amdgcn_s_setprio(0);
  };

  // prologue: 3 subtiles in flight (9 loads/wave outstanding)
  stage(0, 0);
  stage(1, 1);
  stage(2, 2);

  // main loop: 21 iters; stage s+3 (12 outstanding), wait to 9 (= step s
  // landed), barrier, compute, barrier (protects ring slot reuse).
  for (int s = 0; s < 21; ++s) {
    stage((s + 3) & 3, s + 3);
    asm volatile("s_waitcnt vmcnt(9)" ::: "memory");
    __builtin_amdgcn_s_barrier();
    compute(s & 3);
    __builtin_amdgcn_s_barrier();
  }
  // tail drain: 6 -> 3 -> 0
  asm volatile("s_waitcnt vmcnt(6)" ::: "memory");
  __builtin_amdgcn_s_barrier();
  compute(21 & 3);
  __builtin_amdgcn_s_barrier();
  asm volatile("s_waitcnt vmcnt(3)" ::: "memory");
  __builtin_amdgcn_s_barrier();
  compute(22 & 3);
  __builtin_amdgcn_s_barrier();
  asm volatile("s_waitcnt vmcnt(0)" ::: "memory");
  __builtin_amdgcn_s_barrier();
  compute(23 & 3);

  // epilogue: C/D layout col = lane&15, row = (lane>>4)*4 + j
#pragma unroll
  for (int ni = 0; ni < 4; ++ni) {
    const int col = n0 + wc * 64 + ni * 16 + lr;
#pragma unroll
    for (int mi = 0; mi < 4; ++mi) {
      const int row = m0 + wr * 64 + mi * 16 + lg * 4;
      const f32x4 v = acc[mi][ni];
#pragma unroll
      for (int j = 0; j < 4; ++j)
        C[(size_t)(row + j) * DDIM + col] = v[j] + bs[ni];
    }
  }
}

// ---- fallback (ws too small): naive fused f32, correct but slow ----
__global__ __launch_bounds__(256) void naive_kernel(
    const float* __restrict__ x, const int* __restrict__ ys,
    const int* __restrict__ xs, const float* __restrict__ W,
    const float* __restrict__ bias, float* __restrict__ out) {
  __shared__ float prow[FDIM];
  const int tok = blockIdx.x;
  const int t   = threadIdx.x;
  const int b   = tok / NPATCH;
  const int y   = ys[tok];
  const int xc  = xs[tok];
  for (int i = t; i < FDIM; i += 256) {
    int c = i >> 8, rem = i & 255, py = rem >> 4, px = rem & 15;
    prow[i] = x[((size_t)(b * CH + c) * HW + y + py) * HW + xc + px];
  }
  __syncthreads();
  for (int dd = 0; dd < 3; ++dd) {
    const int d = t + dd * 256;
    float s = bias[d];
    const float4* wr = (const float4*)&W[(size_t)d * FDIM];
    const float4* pr = (const float4*)prow;
    for (int f4 = 0; f4 < FDIM / 4; ++f4) {
      float4 wv = wr[f4];
      float4 pv = pr[f4];
      s += wv.x * pv.x + wv.y * pv.y + wv.z * pv.z + wv.w * pv.w;
    }
    out[(size_t)tok * DDIM + d] = s;
  }
  if (t == 0) {
    float* pos = out + OUT_TOKENS;
    pos[(size_t)tok * 2]     = (float)y;
    pos[(size_t)tok * 2 + 1] = (float)xc;
  }
}

extern "C" void kernel_launch(void* const* d_in, const int* in_sizes, int n_in,
                              void* d_out, int out_size, void* d_ws, size_t ws_size,
                              hipStream_t stream) {
  const float* x    = (const float*)d_in[0];
  const int*   ys   = (const int*)d_in[1];
  const int*   xs   = (const int*)d_in[2];
  const float* W    = (const float*)d_in[3];
  const float* bias = (const float*)d_in[4];
  float* out = (float*)d_out;
  float* pos = out + OUT_TOKENS;

  const size_t w_bytes = (size_t)DDIM * FDIM * 2;
  const size_t p_bytes = TOKELEMS * 2;
  if (ws_size >= w_bytes + p_bytes) {
    short* Wbf     = (short*)d_ws;
    short* patches = (short*)d_ws + (size_t)DDIM * FDIM;
    prep_kernel<<<GATHER_BLOCKS + WCONV_BLOCKS, 256, 0, stream>>>(
        x, ys, xs, W, patches, Wbf, pos);
    gemm_kernel<<<(TOKENS / 256) * (DDIM / 128), 512, 0, stream>>>(
        patches, Wbf, bias, out);
  } else {
    naive_kernel<<<TOKENS, 256, 0, stream>>>(x, ys, xs, W, bias, out);
  }
}